// Round 3
// baseline (751.078 us; speedup 1.0000x reference)
//
#include <hip/hip_runtime.h>
#include <hip/hip_bf16.h>
#include <math.h>

#define N_NODES 100000
#define DIM 64
#define BATCH 16        // edges per wave-batch = one MFMA M-tile

typedef __attribute__((ext_vector_type(8))) short short8;
typedef __attribute__((ext_vector_type(4))) float floatx4;
typedef __attribute__((ext_vector_type(4))) unsigned short us4;

__device__ __forceinline__ short f2bf(float x) {           // RNE f32->bf16
    unsigned u = __float_as_uint(x);
    u += 0x7FFF + ((u >> 16) & 1);
    return (short)(u >> 16);
}

// ---------------------------------------------------------------------------
// FALLBACK path (only if ws_size can't hold the bucket table): atomic scatter.
// ---------------------------------------------------------------------------
__global__ __launch_bounds__(256) void scatter_kernel(
    const float* __restrict__ edge_emb, const int* __restrict__ idx,
    __hip_bfloat162* __restrict__ node_sum, float* __restrict__ deg, int n_edges)
{
    long long gid = (long long)blockIdx.x * blockDim.x + threadIdx.x;
    if (gid >= (long long)n_edges * 32) return;
    int e = (int)(gid >> 5);
    int p = (int)(gid & 31);
    float2 ev = ((const float2*)edge_emb)[gid];
    int2 uv = ((const int2*)idx)[e];
    union { unsigned u32; __hip_bfloat162 h; } cv;
    cv.u32 = (unsigned)(unsigned short)f2bf(ev.x)
           | ((unsigned)(unsigned short)f2bf(ev.y) << 16);
    unsafeAtomicAdd(&node_sum[(size_t)uv.x * 32 + p], cv.h);
    unsafeAtomicAdd(&node_sum[(size_t)uv.y * 32 + p], cv.h);
    if (p == 0) {
        unsafeAtomicAdd(&deg[uv.x], 1.f);
        unsafeAtomicAdd(&deg[uv.y], 1.f);
    }
}

// ---------------------------------------------------------------------------
// Phase 1a: counting-sort edges into fixed-capacity per-node buckets.
// CAP=64: table 25.6MB -> L2-resident; degree ~Poisson(20), max over 100K
// nodes ~45, so 64 never trips (guard is paranoia).
// ---------------------------------------------------------------------------
__global__ __launch_bounds__(256) void bucket_fill_kernel(
    const int* __restrict__ idx, unsigned* __restrict__ cnt,
    unsigned* __restrict__ bucket, int cap, int n_edges)
{
    int e = blockIdx.x * 256 + threadIdx.x;
    if (e >= n_edges) return;
    int2 uv = ((const int2*)idx)[e];
    unsigned pu = atomicAdd(&cnt[uv.x], 1u);
    if (pu < (unsigned)cap) bucket[(size_t)uv.x * cap + pu] = (unsigned)e;
    unsigned pv = atomicAdd(&cnt[uv.y], 1u);
    if (pv < (unsigned)cap) bucket[(size_t)uv.y * cap + pv] = (unsigned)e;
}

// ---------------------------------------------------------------------------
// Phase 1b v3: gather-sum, lane-group-per-node, 8-deep MLP.
// 16 lanes x float4 = one full 256B edge row per group-load; 8 rows + the
// next 8 bucket ids in flight per group at all times.
// ---------------------------------------------------------------------------
__global__ __launch_bounds__(256) void gather_sum_kernel(
    const float* __restrict__ edge_emb, const unsigned* __restrict__ bucket,
    const unsigned* __restrict__ cnt, unsigned short* __restrict__ node_sum,
    float* __restrict__ degf, int cap)
{
    const int lane = threadIdx.x & 63;
    const int g = lane >> 4;        // group 0..3 -> node slot within wave
    const int c16 = lane & 15;      // dims c16*4 .. c16*4+3
    const int wslot = threadIdx.x >> 6;
    const int slot0 = (blockIdx.x * 4 + wslot) * 4 + g;
    const int nslots = gridDim.x * 16;
    const float4* emb4 = (const float4*)edge_emb;

    for (int n = slot0; n < N_NODES; n += nslots) {
        unsigned c = cnt[n];                         // uniform within group
        if (c > (unsigned)cap) c = (unsigned)cap;    // paranoia (never trips)
        const unsigned* bptr = bucket + (size_t)n * cap;
        float4 a0 = {0,0,0,0}, a1 = {0,0,0,0}, a2 = {0,0,0,0}, a3 = {0,0,0,0};
        float4 a4 = {0,0,0,0}, a5 = {0,0,0,0}, a6 = {0,0,0,0}, a7 = {0,0,0,0};
        unsigned j = 0;
        if (c >= 8) {
            unsigned i0 = bptr[0], i1 = bptr[1], i2 = bptr[2], i3 = bptr[3];
            unsigned i4 = bptr[4], i5 = bptr[5], i6 = bptr[6], i7 = bptr[7];
            for (; j + 16 <= c; j += 8) {
                unsigned n0 = bptr[j+8],  n1 = bptr[j+9],  n2 = bptr[j+10], n3 = bptr[j+11];
                unsigned n4 = bptr[j+12], n5 = bptr[j+13], n6 = bptr[j+14], n7 = bptr[j+15];
                float4 v0 = emb4[(size_t)i0 * 16 + c16];
                float4 v1 = emb4[(size_t)i1 * 16 + c16];
                float4 v2 = emb4[(size_t)i2 * 16 + c16];
                float4 v3 = emb4[(size_t)i3 * 16 + c16];
                float4 v4 = emb4[(size_t)i4 * 16 + c16];
                float4 v5 = emb4[(size_t)i5 * 16 + c16];
                float4 v6 = emb4[(size_t)i6 * 16 + c16];
                float4 v7 = emb4[(size_t)i7 * 16 + c16];
                a0.x += v0.x; a0.y += v0.y; a0.z += v0.z; a0.w += v0.w;
                a1.x += v1.x; a1.y += v1.y; a1.z += v1.z; a1.w += v1.w;
                a2.x += v2.x; a2.y += v2.y; a2.z += v2.z; a2.w += v2.w;
                a3.x += v3.x; a3.y += v3.y; a3.z += v3.z; a3.w += v3.w;
                a4.x += v4.x; a4.y += v4.y; a4.z += v4.z; a4.w += v4.w;
                a5.x += v5.x; a5.y += v5.y; a5.z += v5.z; a5.w += v5.w;
                a6.x += v6.x; a6.y += v6.y; a6.z += v6.z; a6.w += v6.w;
                a7.x += v7.x; a7.y += v7.y; a7.z += v7.z; a7.w += v7.w;
                i0 = n0; i1 = n1; i2 = n2; i3 = n3;
                i4 = n4; i5 = n5; i6 = n6; i7 = n7;
            }
            {   // drain the preloaded 8
                float4 v0 = emb4[(size_t)i0 * 16 + c16];
                float4 v1 = emb4[(size_t)i1 * 16 + c16];
                float4 v2 = emb4[(size_t)i2 * 16 + c16];
                float4 v3 = emb4[(size_t)i3 * 16 + c16];
                float4 v4 = emb4[(size_t)i4 * 16 + c16];
                float4 v5 = emb4[(size_t)i5 * 16 + c16];
                float4 v6 = emb4[(size_t)i6 * 16 + c16];
                float4 v7 = emb4[(size_t)i7 * 16 + c16];
                a0.x += v0.x; a0.y += v0.y; a0.z += v0.z; a0.w += v0.w;
                a1.x += v1.x; a1.y += v1.y; a1.z += v1.z; a1.w += v1.w;
                a2.x += v2.x; a2.y += v2.y; a2.z += v2.z; a2.w += v2.w;
                a3.x += v3.x; a3.y += v3.y; a3.z += v3.z; a3.w += v3.w;
                a4.x += v4.x; a4.y += v4.y; a4.z += v4.z; a4.w += v4.w;
                a5.x += v5.x; a5.y += v5.y; a5.z += v5.z; a5.w += v5.w;
                a6.x += v6.x; a6.y += v6.y; a6.z += v6.z; a6.w += v6.w;
                a7.x += v7.x; a7.y += v7.y; a7.z += v7.z; a7.w += v7.w;
                j += 8;
            }
        }
        for (; j < c; ++j) {                         // tail 0..7
            float4 v0 = emb4[(size_t)bptr[j] * 16 + c16];
            a0.x += v0.x; a0.y += v0.y; a0.z += v0.z; a0.w += v0.w;
        }
        float sx = ((a0.x + a1.x) + (a2.x + a3.x)) + ((a4.x + a5.x) + (a6.x + a7.x));
        float sy = ((a0.y + a1.y) + (a2.y + a3.y)) + ((a4.y + a5.y) + (a6.y + a7.y));
        float sz = ((a0.z + a1.z) + (a2.z + a3.z)) + ((a4.z + a5.z) + (a6.z + a7.z));
        float sw = ((a0.w + a1.w) + (a2.w + a3.w)) + ((a4.w + a5.w) + (a6.w + a7.w));
        us4 o;
        o[0] = (unsigned short)f2bf(sx);
        o[1] = (unsigned short)f2bf(sy);
        o[2] = (unsigned short)f2bf(sz);
        o[3] = (unsigned short)f2bf(sw);
        *(us4*)&node_sum[(size_t)n * 64 + c16 * 4] = o;   // 16 lanes x 8B = 128B
        if (c16 == 0) degf[n] = (float)c;
    }
}

// ---------------------------------------------------------------------------
// Phase 2 v3: register-direct A-fragments + 2-deep software pipeline.
// idx is pipelined TWO batches ahead (it feeds the dependent deg/ns
// addresses); deg/emb/ns data ONE batch ahead, issued right after the
// current batch's A-fragments are built, so ~12 loads overlap the MFMA +
// epilogue + store. Stages ping-pong via 2x-unrolled loop (no rotation movs).
// mfma_f32_16x16x32_bf16 layouts (m89/m120 verified):
//   A[m=lane&15][k=(lane>>4)*8+j], B[k=(lane>>4)*8+j][n=lane&15],
//   C[row=(lane>>4)*4+reg][col=lane&15]
// ---------------------------------------------------------------------------
struct Stage {
    float du, dv;
    float4 m00, m01, m10, m11;    // emb dims q*8..+7 (kt0), +32.. (kt1)
    uint4 su0, su1, sv0, sv1;     // node_sum bf16x8 per kt per side
};

__device__ __forceinline__ int2 load_uv(const int* __restrict__ idx, int bb, int l15) {
    return ((const int2*)idx)[bb * BATCH + l15];
}

__device__ __forceinline__ void load_data(
    Stage& s, const float* __restrict__ edge_emb,
    const unsigned short* __restrict__ node_sum, const float* __restrict__ deg,
    int2 uv, int bb, int l15, int q)
{
    s.du = deg[uv.x];
    s.dv = deg[uv.y];
    const float4* eb = (const float4*)(edge_emb + ((size_t)(bb * BATCH + l15)) * 64 + q * 8);
    s.m00 = eb[0]; s.m01 = eb[1]; s.m10 = eb[8]; s.m11 = eb[9];
    const unsigned short* nsu = node_sum + (size_t)uv.x * 64 + q * 8;
    const unsigned short* nsv = node_sum + (size_t)uv.y * 64 + q * 8;
    s.su0 = *(const uint4*)nsu; s.su1 = *(const uint4*)(nsu + 32);
    s.sv0 = *(const uint4*)nsv; s.sv1 = *(const uint4*)(nsv + 32);
}

__device__ __forceinline__ short8 mk_frag(uint4 su, float4 m0, float4 m1, float inv) {
    short8 a;
    a[0] = f2bf((__uint_as_float(su.x << 16)         - m0.x) * inv);
    a[1] = f2bf((__uint_as_float(su.x & 0xffff0000u) - m0.y) * inv);
    a[2] = f2bf((__uint_as_float(su.y << 16)         - m0.z) * inv);
    a[3] = f2bf((__uint_as_float(su.y & 0xffff0000u) - m0.w) * inv);
    a[4] = f2bf((__uint_as_float(su.z << 16)         - m1.x) * inv);
    a[5] = f2bf((__uint_as_float(su.z & 0xffff0000u) - m1.y) * inv);
    a[6] = f2bf((__uint_as_float(su.w << 16)         - m1.z) * inv);
    a[7] = f2bf((__uint_as_float(su.w & 0xffff0000u) - m1.w) * inv);
    return a;
}

__device__ __forceinline__ void build_frags(const Stage& s, short8 aU[2], short8 aV[2]) {
    const float invu = (s.du > 1.f) ? 1.f / (s.du - 1.f) : 0.f;
    const float invv = (s.dv > 1.f) ? 1.f / (s.dv - 1.f) : 0.f;
    aU[0] = mk_frag(s.su0, s.m00, s.m01, invu);
    aU[1] = mk_frag(s.su1, s.m10, s.m11, invu);
    aV[0] = mk_frag(s.sv0, s.m00, s.m01, invv);
    aV[1] = mk_frag(s.sv1, s.m10, s.m11, invv);
}

__device__ __forceinline__ void compute_store(
    const short8 aU[2], const short8 aV[2],
    const short (*ldsB)[DIM * 8],
    const float bfv[4], const float bbv[4], const float wgv[4], float bgv,
    float* __restrict__ out, int e0, int q, int l15, int lane)
{
    floatx4 cU[4], cV[4];
#pragma unroll
    for (int nt = 0; nt < 4; ++nt) {
        const short8 b0 = *(const short8*)&ldsB[nt * 2 + 0][lane * 8];
        const short8 b1 = *(const short8*)&ldsB[nt * 2 + 1][lane * 8];
        const short8 g0 = *(const short8*)&ldsB[8 + nt * 2 + 0][lane * 8];
        const short8 g1 = *(const short8*)&ldsB[8 + nt * 2 + 1][lane * 8];
        floatx4 z = {0.f, 0.f, 0.f, 0.f};
        z = __builtin_amdgcn_mfma_f32_16x16x32_bf16(aU[0], b0, z, 0, 0, 0);
        cU[nt] = __builtin_amdgcn_mfma_f32_16x16x32_bf16(aU[1], b1, z, 0, 0, 0);
        floatx4 z2 = {0.f, 0.f, 0.f, 0.f};
        z2 = __builtin_amdgcn_mfma_f32_16x16x32_bf16(aV[0], g0, z2, 0, 0, 0);
        cV[nt] = __builtin_amdgcn_mfma_f32_16x16x32_bf16(aV[1], g1, z2, 0, 0, 0);
    }

    float p[4] = {0.f, 0.f, 0.f, 0.f};
#pragma unroll
    for (int nt = 0; nt < 4; ++nt)
#pragma unroll
        for (int r = 0; r < 4; ++r) {
            float af = cU[nt][r] + bfv[nt];
            float ab = cV[nt][r] + bbv[nt];
            cU[nt][r] = af;
            cV[nt][r] = ab;
            p[r] = fmaf(af + ab, wgv[nt], p[r]);
        }
#pragma unroll
    for (int r = 0; r < 4; ++r) {
        float s = p[r];
        s += __shfl_xor(s, 1);
        s += __shfl_xor(s, 2);
        s += __shfl_xor(s, 4);
        s += __shfl_xor(s, 8);
        p[r] = 1.f / (1.f + __expf(-(s + bgv)));       // gate for edge e0+4q+r
    }
#pragma unroll
    for (int nt = 0; nt < 4; ++nt)
#pragma unroll
        for (int r = 0; r < 4; ++r) {
            const int eo = e0 + q * 4 + r;              // C row = q*4 + r
            out[(size_t)eo * 64 + nt * 16 + l15] =
                fmaf(p[r], cU[nt][r] - cV[nt][r], cV[nt][r]);
        }
}

__global__ __launch_bounds__(256, 3) void fused_edge_kernel(
    const float* __restrict__ edge_emb,
    const int* __restrict__ idx,
    const unsigned short* __restrict__ node_sum,   // bf16 bits
    const float* __restrict__ deg,
    const float* __restrict__ Wf, const float* __restrict__ bf,
    const float* __restrict__ Wb, const float* __restrict__ bb,
    const float* __restrict__ Wg, const float* __restrict__ bg,
    float* __restrict__ out, int n_edges)
{
    __shared__ __align__(16) short ldsB[16][DIM * 8];   // frag f: [lane][8] bf16
    const int lane = threadIdx.x & 63;
    const int l15 = lane & 15;
    const int q = lane >> 4;
    const int wslot = threadIdx.x >> 6;

    // ---- stage Wf/Wb fragments into LDS (once per block), frag = mat*8+nt*2+kt
    for (int f = wslot; f < 16; f += 4) {
        const float* W = (f < 8) ? Wf : Wb;
        const int nt = (f >> 1) & 3, kt = f & 1;
        short8 w;
#pragma unroll
        for (int j = 0; j < 8; ++j)
            w[j] = f2bf(W[(kt * 32 + q * 8 + j) * 64 + nt * 16 + l15]);
        *(short8*)&ldsB[f][lane * 8] = w;
    }
    __syncthreads();

    float bfv[4], bbv[4], wgv[4];
#pragma unroll
    for (int nt = 0; nt < 4; ++nt) {
        bfv[nt] = bf[nt * 16 + l15];
        bbv[nt] = bb[nt * 16 + l15];
        wgv[nt] = Wg[nt * 16 + l15];
    }
    const float bgv = bg[0];

    const int wid = __builtin_amdgcn_readfirstlane(blockIdx.x * 4 + wslot);
    const int nwaves = gridDim.x * 4;
    const int nbatches = n_edges / BATCH;   // E=1M divisible by 16

    int b = wid;
    if (b >= nbatches) return;

    // prologue: current data + next idx
    Stage S0, S1;
    int2 uv0, uv1;
    {
        int2 uvc = load_uv(idx, b, l15);
        load_data(S0, edge_emb, node_sum, deg, uvc, b, l15, q);
        uv0 = load_uv(idx, min(b + nwaves, nbatches - 1), l15);
    }

    // STEP: build frags from CUR; issue next idx + next data; compute/store CUR
#define STEP(CUR, NXT, UVC, UVN)                                              \
    {                                                                         \
        short8 aU[2], aV[2];                                                  \
        build_frags(CUR, aU, aV);                                             \
        const int b2 = b + nwaves;                                            \
        const int last = (b2 >= nbatches);                                    \
        const int bl = last ? b : b2;                                         \
        UVN = load_uv(idx, min(b2 + nwaves, nbatches - 1), l15);              \
        load_data(NXT, edge_emb, node_sum, deg, UVC, bl, l15, q);             \
        compute_store(aU, aV, ldsB, bfv, bbv, wgv, bgv, out,                  \
                      b * BATCH, q, l15, lane);                               \
        if (last) break;                                                      \
        b = b2;                                                               \
    }

    for (;;) {
        STEP(S0, S1, uv0, uv1)
        STEP(S1, S0, uv1, uv0)
    }
#undef STEP
}

extern "C" void kernel_launch(void* const* d_in, const int* in_sizes, int n_in,
                              void* d_out, int out_size, void* d_ws, size_t ws_size,
                              hipStream_t stream) {
    const float* edge_emb = (const float*)d_in[0];
    const float* Wf = (const float*)d_in[1];
    const float* bf = (const float*)d_in[2];
    const float* Wb = (const float*)d_in[3];
    const float* bb = (const float*)d_in[4];
    const float* Wg = (const float*)d_in[5];
    const float* bg = (const float*)d_in[6];
    const int* idx = (const int*)d_in[7];
    float* out = (float*)d_out;

    const int n_edges = in_sizes[7] / 2;

    // Workspace layout:
    //   [0)            node_sum  bf16  N*64*2 = 12.8 MB
    //   [ns)           deg       f32   N*4    = 0.4 MB
    //   [ns+deg)       cnt       u32   N*4    = 0.4 MB
    //   [ns+deg+cnt)   bucket    u32   N*CAP*4 (CAP=64 -> 25.6 MB)
    char* ws = (char*)d_ws;
    const size_t ns_bytes  = (size_t)N_NODES * DIM * 2;
    const size_t deg_bytes = (size_t)N_NODES * 4;
    const size_t cnt_bytes = (size_t)N_NODES * 4;
    unsigned short* node_sum = (unsigned short*)ws;
    float* deg = (float*)(ws + ns_bytes);
    unsigned* cnt = (unsigned*)(ws + ns_bytes + deg_bytes);
    unsigned* bucket = (unsigned*)(ws + ns_bytes + deg_bytes + cnt_bytes);
    const size_t fixed_bytes = ns_bytes + deg_bytes + cnt_bytes;

    int cap = 0;
    if (ws_size >= fixed_bytes + (size_t)N_NODES * 64 * 4) cap = 64;

    if (cap) {
        hipMemsetAsync(cnt, 0, cnt_bytes, stream);
        int blocksF = (n_edges + 255) / 256;
        bucket_fill_kernel<<<blocksF, 256, 0, stream>>>(idx, cnt, bucket, cap, n_edges);
        gather_sum_kernel<<<1563, 256, 0, stream>>>(edge_emb, bucket, cnt,
                                                    node_sum, deg, cap);
    } else {
        hipMemsetAsync(d_ws, 0, ns_bytes + deg_bytes, stream);
        long long sthreads = (long long)n_edges * 32;
        int blocks1 = (int)((sthreads + 255) / 256);
        scatter_kernel<<<blocks1, 256, 0, stream>>>(edge_emb, idx,
            (__hip_bfloat162*)node_sum, deg, n_edges);
    }

    int blocks2 = 2048;   // 8192 waves, ~7.6 batches/wave
    fused_edge_kernel<<<blocks2, 256, 0, stream>>>(
        edge_emb, idx, node_sum, deg,
        Wf, bf, Wb, bb, Wg, bg, out, n_edges);
}